// Round 6
// baseline (23.637 us; speedup 1.0000x reference)
//
#include <hip/hip_runtime.h>
#include <hip/hip_bf16.h>

#define NQ 6
#define DIM 64
#define NLAYERS 6

typedef __attribute__((ext_vector_type(8))) short bf16x8;
typedef __attribute__((ext_vector_type(4))) float f32x4;

// ---------------------------------------------------------------------------
// build_M: fused circuit matrix M = P*U5*...*P*U0*F (complex 64x64), emitted
// as MFMA fragments (bf16 hi/lo split), frag-linear:
//   frag f = (jt*2 + chunk)*4 + plane  (0=r_hi 1=r_lo 2=i_hi 3=i_lo)
//   ushort addr = f*512 + lane16*8 + e
//   lane16 = (j&15) + 16*((k>>3)&3), chunk = k>>5, e = k&7, jt = j>>4.
// Role-agnostic: qenc packs x with the SAME (lanegrp,e)->k mapping, so the
// positional A/B pairing is consistent. (Validated passing in R4.)
// ---------------------------------------------------------------------------
__global__ __launch_bounds__(64) void build_M(const float* __restrict__ w,
                                              unsigned short* __restrict__ Bf) {
    const int k = blockIdx.x;    // column 0..63
    const int j = threadIdx.x;   // row/lane 0..63

    int t = (j * k) & 63;
    float sv, cv;
    sincospif((float)t / 32.0f, &sv, &cv);   // exp(i*pi*t/32)
    float vr = cv * 0.125f;
    float vi = sv * 0.125f;

    int m = j;
#pragma unroll
    for (int q = 0; q < NQ; ++q) {
        int cb = 5 - q;
        int tb = 5 - ((q + 1) % NQ);
        if ((m >> cb) & 1) m ^= (1 << tb);
    }
    const int dst4 = m << 2;

    for (int l = 0; l < NLAYERS; ++l) {
#pragma unroll
        for (int q = 0; q < NQ; ++q) {
            float th = w[l * NQ + q] * 0.5f;
            float c = cosf(th), s = sinf(th);
            int b = 5 - q;
            float pr = __shfl_xor(vr, 1 << b);
            float pi = __shfl_xor(vi, 1 << b);
            float sgn = ((j >> b) & 1) ? s : -s;
            vr = c * vr + sgn * pr;
            vi = c * vi + sgn * pi;
        }
        vr = __int_as_float(__builtin_amdgcn_ds_permute(dst4, __float_as_int(vr)));
        vi = __int_as_float(__builtin_amdgcn_ds_permute(dst4, __float_as_int(vi)));
    }

    const int jt = j >> 4;
    const int lane16 = (j & 15) + 16 * ((k >> 3) & 3);
    const int chunk = k >> 5;
    const int e = k & 7;
    const int base = ((jt * 2 + chunk) * 4) * 512 + lane16 * 8 + e;

    __hip_bfloat16 rh = __float2bfloat16(vr);
    __hip_bfloat16 rl = __float2bfloat16(vr - __bfloat162float(rh));
    __hip_bfloat16 ih = __float2bfloat16(vi);
    __hip_bfloat16 il = __float2bfloat16(vi - __bfloat162float(ih));
    Bf[base]        = *(unsigned short*)&rh;
    Bf[base + 512]  = *(unsigned short*)&rl;
    Bf[base + 1024] = *(unsigned short*)&ih;
    Bf[base + 1536] = *(unsigned short*)&il;
}

__device__ __forceinline__ void split8(const float* f, bf16x8& h, bf16x8& l) {
#pragma unroll
    for (int i = 0; i < 8; ++i) {
        __hip_bfloat16 hh = __float2bfloat16(f[i]);
        __hip_bfloat16 ll = __float2bfloat16(f[i] - __bfloat162float(hh));
        h[i] = *(short*)&hh;
        l[i] = *(short*)&ll;
    }
}

// ---------------------------------------------------------------------------
// qenc_main: M is the A-operand (from LDS), x the B-operand. Wave owns 32
// rows (2 tiles sharing every M ds_read). Epilogue: lane = (batch row r,
// j-quad g) holds out[row0+r][jt*16+4g..+3] -> 8 coalesced float4 stores,
// inv already lane-resident (no shfl).
// ---------------------------------------------------------------------------
__global__ __launch_bounds__(256) void qenc_main(const float* __restrict__ x,
                                                 const unsigned short* __restrict__ Bf,
                                                 float* __restrict__ out) {
    __shared__ __align__(16) unsigned short sB[16384];   // 32 KB
    const int tid = threadIdx.x;
    const int lane = tid & 63;
    const int wid = tid >> 6;
    const int row0 = blockIdx.x * 128 + wid * 32;
    const int r = lane & 15;      // batch row within tile (B-side n index)
    const int g = lane >> 4;      // k-group

    // ---- issue x loads first (overlap with stage+barrier)
    const float* xp0 = x + (size_t)(row0 + r) * DIM + 8 * g;
    const float* xp1 = xp0 + (size_t)16 * DIM;
    float4 v0a = *(const float4*)(xp0);
    float4 v0b = *(const float4*)(xp0 + 4);
    float4 v0c = *(const float4*)(xp0 + 32);
    float4 v0d = *(const float4*)(xp0 + 36);
    float4 v1a = *(const float4*)(xp1);
    float4 v1b = *(const float4*)(xp1 + 4);
    float4 v1c = *(const float4*)(xp1 + 32);
    float4 v1d = *(const float4*)(xp1 + 36);

    // ---- stage M fragments to LDS (linear copy)
    {
        const float4* src = (const float4*)Bf;
        float4* dst = (float4*)sB;
#pragma unroll
        for (int i = 0; i < 8; ++i) dst[tid + 256 * i] = src[tid + 256 * i];
    }

    float xf0[16], xf1[16];
    *(float4*)(xf0)      = v0a;  *(float4*)(xf0 + 4)  = v0b;
    *(float4*)(xf0 + 8)  = v0c;  *(float4*)(xf0 + 12) = v0d;
    *(float4*)(xf1)      = v1a;  *(float4*)(xf1 + 4)  = v1b;
    *(float4*)(xf1 + 8)  = v1c;  *(float4*)(xf1 + 12) = v1d;

    // ---- norms (reduce over the 4 lanes sharing row r)
    float n0 = 0.f, n1 = 0.f;
#pragma unroll
    for (int i = 0; i < 16; ++i) {
        n0 = fmaf(xf0[i], xf0[i], n0);
        n1 = fmaf(xf1[i], xf1[i], n1);
    }
    n0 += __shfl_xor(n0, 16);  n0 += __shfl_xor(n0, 32);
    n1 += __shfl_xor(n1, 16);  n1 += __shfl_xor(n1, 32);
    const float inv0 = 1.0f / n0;
    const float inv1 = 1.0f / n1;

    // ---- hi/lo bf16 x-fragments (chunk c: k = 32c + 8g .. +7)
    bf16x8 x0h[2], x0l[2], x1h[2], x1l[2];
    split8(xf0,     x0h[0], x0l[0]);
    split8(xf0 + 8, x0h[1], x0l[1]);
    split8(xf1,     x1h[0], x1l[0]);
    split8(xf1 + 8, x1h[1], x1l[1]);

    __syncthreads();

    // ---- MFMA main loop: A = M fragment (LDS), B = x fragment (regs)
    const f32x4 z = {0.f, 0.f, 0.f, 0.f};
    f32x4 acr0[4] = {z, z, z, z}, aci0[4] = {z, z, z, z};
    f32x4 acr1[4] = {z, z, z, z}, aci1[4] = {z, z, z, z};
    const unsigned short* bp = sB + lane * 8;

#pragma unroll
    for (int jt = 0; jt < 4; ++jt) {
#pragma unroll
        for (int c = 0; c < 2; ++c) {
            const unsigned short* fb = bp + ((jt * 2 + c) * 4) * 512;
            bf16x8 mrh = *(const bf16x8*)(fb);
            bf16x8 mrl = *(const bf16x8*)(fb + 512);
            bf16x8 mih = *(const bf16x8*)(fb + 1024);
            bf16x8 mil = *(const bf16x8*)(fb + 1536);
            acr0[jt] = __builtin_amdgcn_mfma_f32_16x16x32_bf16(mrh, x0h[c], acr0[jt], 0, 0, 0);
            acr0[jt] = __builtin_amdgcn_mfma_f32_16x16x32_bf16(mrh, x0l[c], acr0[jt], 0, 0, 0);
            acr0[jt] = __builtin_amdgcn_mfma_f32_16x16x32_bf16(mrl, x0h[c], acr0[jt], 0, 0, 0);
            aci0[jt] = __builtin_amdgcn_mfma_f32_16x16x32_bf16(mih, x0h[c], aci0[jt], 0, 0, 0);
            aci0[jt] = __builtin_amdgcn_mfma_f32_16x16x32_bf16(mih, x0l[c], aci0[jt], 0, 0, 0);
            aci0[jt] = __builtin_amdgcn_mfma_f32_16x16x32_bf16(mil, x0h[c], aci0[jt], 0, 0, 0);
            acr1[jt] = __builtin_amdgcn_mfma_f32_16x16x32_bf16(mrh, x1h[c], acr1[jt], 0, 0, 0);
            acr1[jt] = __builtin_amdgcn_mfma_f32_16x16x32_bf16(mrh, x1l[c], acr1[jt], 0, 0, 0);
            acr1[jt] = __builtin_amdgcn_mfma_f32_16x16x32_bf16(mrl, x1h[c], acr1[jt], 0, 0, 0);
            aci1[jt] = __builtin_amdgcn_mfma_f32_16x16x32_bf16(mih, x1h[c], aci1[jt], 0, 0, 0);
            aci1[jt] = __builtin_amdgcn_mfma_f32_16x16x32_bf16(mih, x1l[c], aci1[jt], 0, 0, 0);
            aci1[jt] = __builtin_amdgcn_mfma_f32_16x16x32_bf16(mil, x1h[c], aci1[jt], 0, 0, 0);
        }
    }

    // ---- epilogue: lane holds out[row0+r][jt*16 + 4g + q], q=0..3
    float* op0 = out + (size_t)(row0 + r) * DIM + 4 * g;
    float* op1 = op0 + (size_t)16 * DIM;
#pragma unroll
    for (int jt = 0; jt < 4; ++jt) {
        float4 o0, o1;
        o0.x = (acr0[jt][0] * acr0[jt][0] + aci0[jt][0] * aci0[jt][0]) * inv0;
        o0.y = (acr0[jt][1] * acr0[jt][1] + aci0[jt][1] * aci0[jt][1]) * inv0;
        o0.z = (acr0[jt][2] * acr0[jt][2] + aci0[jt][2] * aci0[jt][2]) * inv0;
        o0.w = (acr0[jt][3] * acr0[jt][3] + aci0[jt][3] * aci0[jt][3]) * inv0;
        o1.x = (acr1[jt][0] * acr1[jt][0] + aci1[jt][0] * aci1[jt][0]) * inv1;
        o1.y = (acr1[jt][1] * acr1[jt][1] + aci1[jt][1] * aci1[jt][1]) * inv1;
        o1.z = (acr1[jt][2] * acr1[jt][2] + aci1[jt][2] * aci1[jt][2]) * inv1;
        o1.w = (acr1[jt][3] * acr1[jt][3] + aci1[jt][3] * aci1[jt][3]) * inv1;
        *(float4*)(op0 + jt * 16) = o0;
        *(float4*)(op1 + jt * 16) = o1;
    }
}

extern "C" void kernel_launch(void* const* d_in, const int* in_sizes, int n_in,
                              void* d_out, int out_size, void* d_ws, size_t ws_size,
                              hipStream_t stream) {
    const float* x = (const float*)d_in[0];
    const float* w = (const float*)d_in[1];
    float* out = (float*)d_out;
    unsigned short* Bf = (unsigned short*)d_ws;   // 32 KB fragment image
    int B = in_sizes[0] / DIM;

    hipLaunchKernelGGL(build_M, dim3(DIM), dim3(64), 0, stream, w, Bf);
    hipLaunchKernelGGL(qenc_main, dim3(B / 128), dim3(256), 0, stream, x, Bf, out);
}